// Round 4
// baseline (90.953 us; speedup 1.0000x reference)
//
#include <hip/hip_runtime.h>

// Problem dims (fixed by reference setup_inputs)
#define BDIM 256
#define IDIM 1024
#define ODIM 1024

#define TILE_OL 2             // output columns per lane (amortizes LDS broadcast)
#define TILE_O (64 * TILE_OL) // 128 outputs per block
#define TILE_B 4              // batch rows per thread
#define NW 8                  // waves per block, each owns an i-eighth
#define QLEN (IDIM / NW)      // 128 i per wave
#define CHUNK 8               // i per w-prefetch chunk
#define NCHUNK (QLEN / CHUNK) // 16 chunks

typedef float v2f __attribute__((ext_vector_type(2)));
typedef float v4f __attribute__((ext_vector_type(4)));

#if __has_builtin(__builtin_amdgcn_exp2f)
#define FAST_EXP2(v) __builtin_amdgcn_exp2f(v)
#else
#define FAST_EXP2(v) exp2f(v)
#endif

__global__ __launch_bounds__(512, 4)
void stl_kernel(const float* __restrict__ x,
                const float* __restrict__ w,
                const float* __restrict__ bias,
                float* __restrict__ out) {
  __shared__ float xs[TILE_B][IDIM];    // 16 KB: 4 x rows, prescaled by log2e
  __shared__ float ps[NW][64][16];      // 32 KB: per-wave partials (2 o-sets)

  const int tx = threadIdx.x;          // 0..63 -> output column (lane)
  const int ty = threadIdx.y;          // 0..7  -> i-eighth (one wave each)
  const int tid = ty * 64 + tx;
  const int o0 = blockIdx.x * TILE_O;
  const int b0 = blockIdx.y * TILE_B;

  const float LOG2E = 1.4426950408889634f;  // folds 1/TEMPERATURE too

  // ---- Stage 4 x rows once (coalesced, prescaled). Barrier #1. ----
#pragma unroll
  for (int k = 0; k < 2; ++k) {
    int f = tid + k * 512;             // 0..1023 float4s
    int row = f >> 8;                  // 256 float4 per row
    int col = f & 255;
    float4 v = ((const float4*)(x + (size_t)(b0 + row) * IDIM))[col];
    v.x *= LOG2E; v.y *= LOG2E; v.z *= LOG2E; v.w *= LOG2E;
    ((float4*)(&xs[row][0]))[col] = v;
  }
  __syncthreads();

  const int qbase = ty * QLEN;
  // Lane owns columns o0+tx and o0+tx+64: second column is a +256B immediate
  // offset off the SAME address chain (no extra address VGPRs).
  const float* wp = w + (size_t)qbase * ODIM + o0 + tx;

  // Accumulators: [o-set][batch row], packed over i-pairs -> all v_pk_*.
  v2f an[TILE_OL][TILE_B], ad[TILE_OL][TILE_B];
#pragma unroll
  for (int s = 0; s < TILE_OL; ++s)
#pragma unroll
    for (int r = 0; r < TILE_B; ++r) { an[s][r] = (v2f){0.f, 0.f}; ad[s][r] = (v2f){0.f, 0.f}; }

  // w chunk double buffer: per o-set, 4 i-pairs (v2f -> aligned VGPR pairs).
  v2f wA0[CHUNK / 2], wA1[CHUNK / 2], wB0[CHUNK / 2], wB1[CHUNK / 2];

#define WLOAD(d0, d1, cc)                                                 \
  {                                                                       \
    const float* wq = wp + (size_t)((cc) * CHUNK) * ODIM;                 \
    _Pragma("unroll")                                                     \
    for (int u = 0; u < CHUNK / 2; ++u) {                                 \
      d0[u].x = wq[(size_t)(2 * u) * ODIM];                               \
      d0[u].y = wq[(size_t)(2 * u + 1) * ODIM];                           \
      d1[u].x = wq[(size_t)(2 * u) * ODIM + 64];                          \
      d1[u].y = wq[(size_t)(2 * u + 1) * ODIM + 64];                      \
    }                                                                     \
  }

#define ROWP(acc_n, acc_d, xpair, wpair)                                  \
  {                                                                       \
    v2f p = (xpair) * (wpair);          /* v_pk_mul */                    \
    v2f t;                                                                \
    t.x = FAST_EXP2(__builtin_fabsf(p.x));  /* v_exp_f32 w/ abs */        \
    t.y = FAST_EXP2(__builtin_fabsf(p.y));                                \
    acc_n += p * t;                     /* v_pk_fma */                    \
    acc_d += t;                         /* v_pk_add */                    \
  }

#define LO(xq) __builtin_shufflevector(xq, xq, 0, 1)
#define HI(xq) __builtin_shufflevector(xq, xq, 2, 3)

  // One 8-i chunk: 8 broadcast ds_read_b128 serve 64 elements (2 o-sets x
  // 4 b x 8 i) -> per-CU LDS pressure halved vs 1 o per lane.
#define COMPUTE(wc0, wc1, cc)                                             \
  {                                                                       \
    const int jb = qbase + (cc) * CHUNK;                                  \
    _Pragma("unroll")                                                     \
    for (int h = 0; h < 2; ++h) {                                         \
      v4f xq[TILE_B];                                                     \
      _Pragma("unroll")                                                   \
      for (int r = 0; r < TILE_B; ++r)                                    \
        xq[r] = *(const v4f*)(&xs[r][jb + h * 4]);                        \
      _Pragma("unroll")                                                   \
      for (int r = 0; r < TILE_B; ++r) {                                  \
        ROWP(an[0][r], ad[0][r], LO(xq[r]), wc0[h * 2])                   \
        ROWP(an[0][r], ad[0][r], HI(xq[r]), wc0[h * 2 + 1])               \
        ROWP(an[1][r], ad[1][r], LO(xq[r]), wc1[h * 2])                   \
        ROWP(an[1][r], ad[1][r], HI(xq[r]), wc1[h * 2 + 1])               \
      }                                                                   \
    }                                                                     \
  }

  // ---- Software-pipelined main loop: w loads one chunk ahead. ----
  WLOAD(wA0, wA1, 0)
  for (int c = 0; c < NCHUNK; c += 2) {
    WLOAD(wB0, wB1, c + 1)
    COMPUTE(wA0, wA1, c)
    WLOAD(wA0, wA1, (c + 2) & (NCHUNK - 1))  // wrap: one harmless reload
    COMPUTE(wB0, wB1, c + 1)
  }

  // ---- Cross-wave combine (barrier #2) ----
#pragma unroll
  for (int s = 0; s < TILE_OL; ++s) {
    *(float4*)(&ps[ty][tx][s * 8 + 0]) =
        make_float4(an[s][0].x + an[s][0].y, an[s][1].x + an[s][1].y,
                    an[s][2].x + an[s][2].y, an[s][3].x + an[s][3].y);
    *(float4*)(&ps[ty][tx][s * 8 + 4]) =
        make_float4(ad[s][0].x + ad[s][0].y, ad[s][1].x + ad[s][1].y,
                    ad[s][2].x + ad[s][2].y, ad[s][3].x + ad[s][3].y);
  }
  __syncthreads();

  if (ty == 0) {
    const float LN2 = 0.6931471805599453f;
    const float scale = (float)IDIM * LN2;   // undo log2e, apply n=IDIM
#pragma unroll
    for (int s = 0; s < TILE_OL; ++s) {
      float n[4] = {0, 0, 0, 0}, d[4] = {0, 0, 0, 0};
#pragma unroll
      for (int q = 0; q < NW; ++q) {
        float4 a = *(const float4*)(&ps[q][tx][s * 8 + 0]);
        float4 b2 = *(const float4*)(&ps[q][tx][s * 8 + 4]);
        n[0] += a.x; n[1] += a.y; n[2] += a.z; n[3] += a.w;
        d[0] += b2.x; d[1] += b2.y; d[2] += b2.z; d[3] += b2.w;
      }
      const int o = o0 + tx + s * 64;
      const float bo = bias[o];
#pragma unroll
      for (int r = 0; r < 4; ++r)
        out[(size_t)(b0 + r) * ODIM + o] = scale * n[r] / d[r] + bo;
    }
  }
}

extern "C" void kernel_launch(void* const* d_in, const int* in_sizes, int n_in,
                              void* d_out, int out_size, void* d_ws, size_t ws_size,
                              hipStream_t stream) {
  const float* x = (const float*)d_in[0];    // [256,1024] f32
  const float* w = (const float*)d_in[1];    // [1024,1024] f32
  const float* b = (const float*)d_in[2];    // [1024] f32
  float* out = (float*)d_out;                // [256,1024] f32

  dim3 grid(ODIM / TILE_O, BDIM / TILE_B);   // (8, 64) = 512 blocks = 2/CU
  dim3 block(64, NW);                        // 512 threads = 8 waves
  stl_kernel<<<grid, block, 0, stream>>>(x, w, b, out);
}